// Round 13
// baseline (1196.437 us; speedup 1.0000x reference)
//
#include <hip/hip_runtime.h>
#include <hip/hip_bf16.h>
#include <math.h>

// Problem constants
#define BB 4
#define LL 1024
#define BL (BB*LL)          // 4096 tokens
#define DD 256
#define VV 32000
#define HH 4
#define DH 64
#define SS 16
#define DCC 4
#define DII 512

typedef float f32x4 __attribute__((ext_vector_type(4)));
typedef short bh8  __attribute__((ext_vector_type(8)));   // 8 bf16 (bit pattern)
typedef unsigned short u16;

// native-rate transcendentals (v_exp_f32 / v_log_f32)
__device__ __forceinline__ float ex_f(float x) { return __expf(x); }
__device__ __forceinline__ float sp_f(float x) {        // softplus
    return fmaxf(x, 0.f) + __logf(1.f + __expf(-fabsf(x)));
}
__device__ __forceinline__ float silu_f(float x) {
    return x / (1.f + __expf(-x));
}
__device__ __forceinline__ short f2bf(float f) {
    __hip_bfloat16 h = __float2bfloat16(f);
    short s; __builtin_memcpy(&s, &h, 2); return s;
}
__device__ __forceinline__ float bf2f(u16 u) {
    unsigned v = ((unsigned)u) << 16;
    float f; __builtin_memcpy(&f, &v, 4); return f;
}

// ---------------------------------------------------------------- all weights fp32->bf16 (one pass, incl lm_w)
#define WB_TOT 5668864
#define LM_TOT 8192000
__global__ void cvtall_k(const float* __restrict__ te_w, const float* __restrict__ a_qkv,
                         const float* __restrict__ a_out, const float* __restrict__ a_ff1,
                         const float* __restrict__ a_ff2, const float* __restrict__ m_in,
                         const float* __restrict__ m_out, const float* __restrict__ m_dt,
                         const float* __restrict__ m_xp, const float* __restrict__ lm,
                         u16* __restrict__ dst, u16* __restrict__ dlm) {
    long i = ((long)blockIdx.x * 256 + threadIdx.x) * 4;
    const float* src; long off; u16* d; long doff;
    if (i >= WB_TOT) {
        long j = i - WB_TOT;
        if (j >= LM_TOT) return;
        src = lm; off = j; d = dlm; doff = j;
    } else {
        d = dst; doff = i;
        if      (i < 65536)   { src = te_w;  off = i; }
        else if (i < 458752)  { src = a_qkv; off = i - 65536; }
        else if (i < 589824)  { src = a_out; off = i - 458752; }
        else if (i < 1114112) { src = a_ff1; off = i - 589824; }
        else if (i < 1638400) { src = a_ff2; off = i - 1114112; }
        else if (i < 3211264) { src = m_in;  off = i - 1638400; }
        else if (i < 3997696) { src = m_out; off = i - 3211264; }
        else {
            long l = i - 3997696;
            int mi = (int)(l / 278528);
            long r = l - (long)mi * 278528;
            if (r < 262144) { src = m_dt + (long)mi * 262144; off = r; }
            else            { src = m_xp + (long)mi * 16384;  off = r - 262144; }
        }
    }
    float4 v = *(const float4*)(src + off);
    ushort4 u;
    u.x = (u16)f2bf(v.x); u.y = (u16)f2bf(v.y);
    u.z = (u16)f2bf(v.z); u.w = (u16)f2bf(v.w);
    *(ushort4*)(d + doff) = u;
}

// ---------------------------------------------------------------- time feat (bf16 out)
__global__ void feat_k(const float* __restrict__ ts, const float* __restrict__ freq,
                       const float* __restrict__ phase, u16* __restrict__ feat) {
    int row = blockIdx.x, t = threadIdx.x;
    float tv = ts[row];
    int d = t & 127;
    float f = sp_f(freq[d]);
    float arg = tv * f + phase[d];
    feat[(size_t)row * DD + t] = (u16)f2bf((t < 128) ? sinf(arg) : cosf(arg));
}

// ---------------------------------------------------------------- layernorm (final only, bf16 out)
__global__ void ln_k(const float* __restrict__ x, const float* __restrict__ g,
                     const float* __restrict__ bbias, u16* __restrict__ out) {
    __shared__ float red[8];
    int row = blockIdx.x, t = threadIdx.x;
    float v = x[(size_t)row * DD + t];
    float s = v;
    #pragma unroll
    for (int o = 32; o >= 1; o >>= 1) s += __shfl_xor(s, o);
    if ((t & 63) == 0) red[t >> 6] = s;
    __syncthreads();
    float mean = (red[0] + red[1] + red[2] + red[3]) * (1.f / 256.f);
    float d = v - mean;
    float s2 = d * d;
    #pragma unroll
    for (int o = 32; o >= 1; o >>= 1) s2 += __shfl_xor(s2, o);
    if ((t & 63) == 0) red[4 + (t >> 6)] = s2;
    __syncthreads();
    float var = (red[4] + red[5] + red[6] + red[7]) * (1.f / 256.f);
    out[(size_t)row * DD + t] = (u16)f2bf(d * rsqrtf(var + 1e-5f) * g[t] + bbias[t]);
}

// ---------------------------------------------------------------- LN-fused 64x64-tile MFMA GEMM (K=256 fixed)
template <int ACT, bool BOUT, bool VT>
__global__ __launch_bounds__(256) void lngemm_k(
    const float* __restrict__ X, const float* __restrict__ g, const float* __restrict__ bb,
    const u16* __restrict__ W, void* __restrict__ outv, u16* __restrict__ vt,
    int M, int N) {
    __shared__ __align__(16) char Abf[32768];   // 64 rows x 256 bf16, swizzled
    __shared__ __align__(16) char Ws[8192];     // 64 rows x 64 bf16 per k-step
    __shared__ float gs[256], bs[256];
    int tid = threadIdx.x;
    int bm = blockIdx.y * 64, bn = blockIdx.x * 64;
    gs[tid] = g[tid]; bs[tid] = bb[tid];

    int row = tid >> 2, part = tid & 3;
    const float* xr = X + (size_t)(bm + row) * 256 + part * 64;
    float4 vv[16];
    float s = 0.f, sq = 0.f;
    #pragma unroll
    for (int i = 0; i < 16; ++i) {
        vv[i] = *(const float4*)(xr + i * 4);
        s  += vv[i].x + vv[i].y + vv[i].z + vv[i].w;
        sq += vv[i].x * vv[i].x + vv[i].y * vv[i].y + vv[i].z * vv[i].z + vv[i].w * vv[i].w;
    }
    s += __shfl_xor(s, 1);  s += __shfl_xor(s, 2);
    sq += __shfl_xor(sq, 1); sq += __shfl_xor(sq, 2);
    float mean = s * (1.f / 256.f);
    float rstd = rsqrtf(sq * (1.f / 256.f) - mean * mean + 1e-5f);
    __syncthreads();   // gs/bs visible
    #pragma unroll
    for (int i8 = 0; i8 < 8; ++i8) {
        bh8 p;
        #pragma unroll
        for (int j = 0; j < 8; ++j) {
            int e = i8 * 8 + j;
            float v = (j & 3) == 0 ? vv[e >> 2].x : (j & 3) == 1 ? vv[e >> 2].y
                    : (j & 3) == 2 ? vv[e >> 2].z : vv[e >> 2].w;
            int c = part * 64 + e;
            p[j] = f2bf((v - mean) * rstd * gs[c] + bs[c]);
        }
        *(bh8*)(Abf + (unsigned)((row * 512 + part * 128 + i8 * 16) ^ ((row & 7) << 4))) = p;
    }
    __syncthreads();

    int lane = tid & 63, wv = tid >> 6;
    int wm = wv >> 1, wn = wv & 1;
    int ro = lane & 15, kg = lane >> 4;
    f32x4 acc[2][2];
    #pragma unroll
    for (int i = 0; i < 2; ++i)
        #pragma unroll
        for (int j = 0; j < 2; ++j) acc[i][j] = (f32x4){0.f, 0.f, 0.f, 0.f};

    const u16* gw = W + (size_t)(bn + row) * 256 + part * 16;
    bool wvalid = (bn + row) < N;
    unsigned swb = (unsigned)(row * 128 + part * 32);
    unsigned sx  = (unsigned)((row & 7) << 4);
    for (int kk = 0; kk < 256; kk += 64) {
        if (kk) __syncthreads();
        bh8 w0 = {}, w1 = {};
        if (wvalid) { w0 = *(const bh8*)(gw + kk); w1 = *(const bh8*)(gw + kk + 8); }
        *(bh8*)(Ws + (swb ^ sx)) = w0;
        *(bh8*)(Ws + ((swb + 16) ^ sx)) = w1;
        __syncthreads();
        #pragma unroll
        for (int ks = 0; ks < 2; ++ks) {
            bh8 af[2], bf_[2];
            #pragma unroll
            for (int m = 0; m < 2; ++m) {
                int r = wm * 32 + m * 16 + ro;
                af[m] = *(const bh8*)(Abf + (unsigned)((r * 512 + kk * 2 + ks * 64 + kg * 16) ^ ((r & 7) << 4)));
            }
            #pragma unroll
            for (int n = 0; n < 2; ++n) {
                int r = wn * 32 + n * 16 + ro;
                bf_[n] = *(const bh8*)(Ws + (unsigned)((r * 128 + ks * 64 + kg * 16) ^ ((r & 7) << 4)));
            }
            #pragma unroll
            for (int m = 0; m < 2; ++m)
                #pragma unroll
                for (int n = 0; n < 2; ++n)
                    acc[m][n] = __builtin_amdgcn_mfma_f32_16x16x32_bf16(af[m], bf_[n], acc[m][n], 0, 0, 0);
        }
    }

    float* outf = (float*)outv;
    u16*   outb = (u16*)outv;
    int cr = (lane >> 4) * 4, cc = lane & 15;
    #pragma unroll
    for (int mf = 0; mf < 2; ++mf) {
        #pragma unroll
        for (int nf = 0; nf < 2; ++nf) {
            int n = bn + wn * 32 + nf * 16 + cc;
            if (n >= N) continue;
            int mbase = bm + wm * 32 + mf * 16 + cr;
            f32x4 a = acc[mf][nf];
            #pragma unroll
            for (int r = 0; r < 4; ++r) {
                float v = a[r];
                if (ACT == 1) v = silu_f(v);
                if (BOUT) outb[(size_t)(mbase + r) * N + n] = (u16)f2bf(v);
                else      outf[(size_t)(mbase + r) * N + n] = v;
            }
            if (VT && n >= 512) {
                int hh = (n - 512) >> 6, dd = (n - 512) & 63;
                int b_ = mbase >> 10, l = mbase & 1023;
                ushort4 uv;
                uv.x = (u16)f2bf(acc[mf][nf][0]); uv.y = (u16)f2bf(acc[mf][nf][1]);
                uv.z = (u16)f2bf(acc[mf][nf][2]); uv.w = (u16)f2bf(acc[mf][nf][3]);
                *(ushort4*)(vt + ((((size_t)b_ * HH + hh) * DH + dd) << 10) + l) = uv;
            }
        }
    }
}

// ---------------------------------------------------------------- 64x64-tile MFMA GEMM (dtx)
// ACT 3: dtx (n<512: softplus+bias -> outf; else raw -> out2)
template <int ACT, bool HASB, bool HASR, bool BOUT>
__global__ __launch_bounds__(256) void bgemm_k(
    const u16* __restrict__ A, const u16* __restrict__ W,
    const float* __restrict__ bias, const float* __restrict__ res,
    void* __restrict__ outv, float* __restrict__ out2, int M, int N, int K) {
    __shared__ __align__(16) char lds[16384];
    char* As = lds;
    char* Ws = lds + 8192;
    int tid = threadIdx.x;
    int bm = blockIdx.y * 64, bn = blockIdx.x * 64;
    int row = tid >> 2, q = tid & 3;
    int lane = tid & 63, wv = tid >> 6;
    int wm = wv >> 1, wn = wv & 1;
    int ro = lane & 15, kg = lane >> 4;

    f32x4 acc[2][2];
    #pragma unroll
    for (int i = 0; i < 2; ++i)
        #pragma unroll
        for (int j = 0; j < 2; ++j) acc[i][j] = (f32x4){0.f, 0.f, 0.f, 0.f};

    const u16* ga = A + (size_t)(bm + row) * K + q * 16;
    const u16* gw = W + (size_t)(bn + row) * K + q * 16;
    bool wvalid = (bn + row) < N;
    unsigned swb = (unsigned)(row * 128 + q * 32);
    unsigned sx  = (unsigned)((row & 7) << 4);

    for (int kk = 0; kk < K; kk += 64) {
        if (kk) __syncthreads();
        {
            *(bh8*)(As + (swb ^ sx)) = *(const bh8*)(ga);
            *(bh8*)(As + ((swb + 16) ^ sx)) = *(const bh8*)(ga + 8);
            bh8 w0 = {}, w1 = {};
            if (wvalid) { w0 = *(const bh8*)(gw); w1 = *(const bh8*)(gw + 8); }
            *(bh8*)(Ws + (swb ^ sx)) = w0;
            *(bh8*)(Ws + ((swb + 16) ^ sx)) = w1;
        }
        ga += 64; gw += 64;
        __syncthreads();
        #pragma unroll
        for (int ks = 0; ks < 2; ++ks) {
            bh8 af[2], bf_[2];
            #pragma unroll
            for (int m = 0; m < 2; ++m) {
                int r = wm * 32 + m * 16 + ro;
                af[m] = *(const bh8*)(As + (unsigned)((r * 128 + ks * 64 + kg * 16) ^ ((r & 7) << 4)));
            }
            #pragma unroll
            for (int n = 0; n < 2; ++n) {
                int r = wn * 32 + n * 16 + ro;
                bf_[n] = *(const bh8*)(Ws + (unsigned)((r * 128 + ks * 64 + kg * 16) ^ ((r & 7) << 4)));
            }
            #pragma unroll
            for (int m = 0; m < 2; ++m)
                #pragma unroll
                for (int n = 0; n < 2; ++n)
                    acc[m][n] = __builtin_amdgcn_mfma_f32_16x16x32_bf16(af[m], bf_[n], acc[m][n], 0, 0, 0);
        }
    }

    float* outf = (float*)outv;
    u16*   outb = (u16*)outv;
    int cr = (lane >> 4) * 4, cc = lane & 15;
    #pragma unroll
    for (int mf = 0; mf < 2; ++mf) {
        #pragma unroll
        for (int nf = 0; nf < 2; ++nf) {
            int n = bn + wn * 32 + nf * 16 + cc;
            if (n >= N) continue;
            int mbase = bm + wm * 32 + mf * 16 + cr;
            f32x4 a = acc[mf][nf];
            #pragma unroll
            for (int r = 0; r < 4; ++r) {
                float v = a[r];
                int m = mbase + r;
                if (ACT == 3) {
                    if (n < 512) outf[(size_t)m * 512 + n] = sp_f(v + bias[n]);
                    else         out2[(size_t)m * 32 + (n - 512)] = v;
                } else {
                    if (HASB) v += bias[n];
                    if (ACT == 1) v = silu_f(v);
                    if (HASR) v += res[(size_t)m * N + n];
                    if (BOUT) outb[(size_t)m * N + n] = (u16)f2bf(v);
                    else      outf[(size_t)m * N + n] = v;
                }
            }
        }
    }
}

// ---------------------------------------------------------------- 32x64-tile GEMM, 2 blocks/CU for N=256 sites
template <int ACT, bool HASB, bool HASR>
__global__ __launch_bounds__(256) void bgemm32_k(
    const u16* __restrict__ A, const u16* __restrict__ W,
    const float* __restrict__ bias, const float* __restrict__ res,
    float* __restrict__ out, int M, int N, int K,
    const int* __restrict__ ids, const int* __restrict__ typ,
    const float* __restrict__ tok, const float* __restrict__ tpe) {
    __shared__ __align__(16) char As[4096];     // 32 rows x 64 bf16
    __shared__ __align__(16) char Ws[8192];     // 64 rows x 64 bf16
    int tid = threadIdx.x;
    int bm = blockIdx.y * 32, bn = blockIdx.x * 64;
    int lane = tid & 63, wv = tid >> 6;
    int wm = wv >> 1, wn = wv & 1;              // wave: 16 rows x 32 cols
    int ro = lane & 15, kg = lane >> 4;

    f32x4 acc[2];
    acc[0] = (f32x4){0.f, 0.f, 0.f, 0.f};
    acc[1] = (f32x4){0.f, 0.f, 0.f, 0.f};

    int arow = tid >> 3, aq = tid & 7;
    const u16* ga = A + (size_t)(bm + arow) * K + aq * 8;
    unsigned aswb = (unsigned)(arow * 128 + aq * 16);
    unsigned asx  = (unsigned)((arow & 7) << 4);
    int wrow = tid >> 2, wq = tid & 3;
    const u16* gw = W + (size_t)(bn + wrow) * K + wq * 16;
    unsigned wswb = (unsigned)(wrow * 128 + wq * 32);
    unsigned wsx  = (unsigned)((wrow & 7) << 4);

    for (int kk = 0; kk < K; kk += 64) {
        if (kk) __syncthreads();
        *(bh8*)(As + (aswb ^ asx)) = *(const bh8*)(ga);
        *(bh8*)(Ws + (wswb ^ wsx)) = *(const bh8*)(gw);
        *(bh8*)(Ws + ((wswb + 16) ^ wsx)) = *(const bh8*)(gw + 8);
        ga += 64; gw += 64;
        __syncthreads();
        #pragma unroll
        for (int ks = 0; ks < 2; ++ks) {
            int r = wm * 16 + ro;
            bh8 af = *(const bh8*)(As + (unsigned)((r * 128 + ks * 64 + kg * 16) ^ ((r & 7) << 4)));
            #pragma unroll
            for (int n = 0; n < 2; ++n) {
                int rr = wn * 32 + n * 16 + ro;
                bh8 bf_ = *(const bh8*)(Ws + (unsigned)((rr * 128 + ks * 64 + kg * 16) ^ ((rr & 7) << 4)));
                acc[n] = __builtin_amdgcn_mfma_f32_16x16x32_bf16(af, bf_, acc[n], 0, 0, 0);
            }
        }
    }

    int cr = (lane >> 4) * 4, cc = lane & 15;
    #pragma unroll
    for (int nf = 0; nf < 2; ++nf) {
        int n = bn + wn * 32 + nf * 16 + cc;
        int mbase = bm + wm * 16 + cr;
        #pragma unroll
        for (int r = 0; r < 4; ++r) {
            float v = acc[nf][r];
            int m = mbase + r;
            if (ACT == 4) {
                v += bias[n] + tok[(size_t)ids[m] * DD + n] + tpe[(size_t)typ[m] * DD + n];
            } else {
                if (HASB) v += bias[n];
                if (HASR) v += res[(size_t)m * N + n];
            }
            out[(size_t)m * N + n] = v;
        }
    }
}

// ---------------------------------------------------------------- lm-head GEMM: bf16 A and W, XCD-chunked
__global__ __launch_bounds__(256) void mgemmL_k(
    const u16* __restrict__ A, const u16* __restrict__ W,
    float* __restrict__ out, int M, int N, int K) {
    __shared__ __align__(16) char lds[32768];
    char* As = lds;
    char* Ws = lds + 16384;
    int lid = blockIdx.y * 32 + blockIdx.x;
    int xcd = lid & 7, wk = lid >> 3;
    int nt = xcd * 32 + (wk >> 5);
    int mt = wk & 31;
    if (nt * 128 >= N) return;
    int bm = mt * 128, bn = nt * 128;

    int tid = threadIdx.x;
    int row = tid >> 1, half = tid & 1;
    int lane = tid & 63, wv = tid >> 6;
    int wm = wv >> 1, wn = wv & 1;
    int ro = lane & 15, kg = lane >> 4;

    f32x4 acc[4][4];
    #pragma unroll
    for (int i = 0; i < 4; ++i)
        #pragma unroll
        for (int j = 0; j < 4; ++j) acc[i][j] = (f32x4){0.f, 0.f, 0.f, 0.f};

    const u16* ga = A + (size_t)(bm + row) * K + half * 32;
    const u16* gw = W + (size_t)(bn + row) * K + half * 32;
    unsigned swb = (unsigned)(row * 128 + half * 64);
    unsigned sx  = (unsigned)((row & 7) << 4);

    for (int kk = 0; kk < K; kk += 64) {
        if (kk) __syncthreads();
        #pragma unroll
        for (int j = 0; j < 4; ++j) {
            *(bh8*)(As + ((swb + j * 16) ^ sx)) = *(const bh8*)(ga + j * 8);
            *(bh8*)(Ws + ((swb + j * 16) ^ sx)) = *(const bh8*)(gw + j * 8);
        }
        ga += 64; gw += 64;
        __syncthreads();
        #pragma unroll
        for (int ks = 0; ks < 2; ++ks) {
            bh8 af[4], bf_[4];
            #pragma unroll
            for (int m = 0; m < 4; ++m) {
                int r = wm * 64 + m * 16 + ro;
                af[m] = *(const bh8*)(As + (unsigned)((r * 128 + ks * 64 + kg * 16) ^ ((r & 7) << 4)));
            }
            #pragma unroll
            for (int n = 0; n < 4; ++n) {
                int r = wn * 64 + n * 16 + ro;
                bf_[n] = *(const bh8*)(Ws + (unsigned)((r * 128 + ks * 64 + kg * 16) ^ ((r & 7) << 4)));
            }
            #pragma unroll
            for (int m = 0; m < 4; ++m)
                #pragma unroll
                for (int n = 0; n < 4; ++n)
                    acc[m][n] = __builtin_amdgcn_mfma_f32_16x16x32_bf16(af[m], bf_[n], acc[m][n], 0, 0, 0);
        }
    }

    int cr = (lane >> 4) * 4, cc = lane & 15;
    #pragma unroll
    for (int mf = 0; mf < 4; ++mf) {
        #pragma unroll
        for (int nf = 0; nf < 4; ++nf) {
            int n = bn + wn * 64 + nf * 16 + cc;
            int mbase = bm + wm * 64 + mf * 16 + cr;
            f32x4 a = acc[mf][nf];
            #pragma unroll
            for (int r = 0; r < 4; ++r)
                out[(size_t)(mbase + r) * N + n] = a[r];
        }
    }
}

// ---------------------------------------------------------------- depthwise causal conv + silu (bf16 in/out)
__global__ void conv_k(const u16* __restrict__ xz, const float* __restrict__ w,
                       const float* __restrict__ cb, u16* __restrict__ xbb) {
    int idx = blockIdx.x * blockDim.x + threadIdx.x;  // BL*DI
    int c = idx & (DII - 1);
    int row = idx >> 9;
    int l = row & (LL - 1);
    int base = row - l;
    const float* wc = w + c * DCC;
    float s = cb[c];
    #pragma unroll
    for (int j = 0; j < DCC; ++j) {
        int ll = l - (DCC - 1) + j;
        if (ll >= 0) s = fmaf(wc[j], bf2f(xz[((size_t)(base + ll)) * (2 * DII) + c]), s);
    }
    xbb[(size_t)idx] = (u16)f2bf(silu_f(s));
}

// ---------------------------------------------------------------- fused selective scan: one block per (b,di)
// Phase 2 now wave-level: 6 shfl_up rounds in-register (no LDS array, no barriers),
// tiny LDS table for the 4 wave totals, register compose for wave prefix.
__global__ __launch_bounds__(256) void scan_k(
    const float* __restrict__ dt, const u16* __restrict__ xb,
    const float* __restrict__ bc, const u16* __restrict__ xz,
    const float* __restrict__ Alog, const float* __restrict__ Dp,
    u16* __restrict__ y) {
    __shared__ float wta[4][SS];   // wave total a
    __shared__ float wtb[4][SS];   // wave total b
    int di = blockIdx.x & (DII - 1);
    int b  = blockIdx.x >> 9;
    int t  = threadIdx.x;
    int lane = t & 63, wvi = t >> 6;
    int l0 = t * 4;
    size_t rb = (size_t)(b * LL + l0);

    float A[SS];
    #pragma unroll
    for (int s = 0; s < SS; ++s) A[s] = -ex_f(Alog[di * SS + s]);

    float dtv[4], xv[4];
    #pragma unroll
    for (int j = 0; j < 4; ++j) {
        dtv[j] = dt[(rb + j) * DII + di];
        xv[j]  = bf2f(xb[(rb + j) * DII + di]);
    }

    // phase 1: thread-local affine compose over its 4 timesteps
    float Pa[SS], Ph[SS];
    #pragma unroll
    for (int j = 0; j < 4; ++j) {
        float u = dtv[j] * xv[j];
        const float* bt = bc + (rb + j) * (2 * SS);
        #pragma unroll
        for (int s = 0; s < SS; ++s) {
            float a = ex_f(dtv[j] * A[s]);
            float w = u * bt[s];
            if (j == 0) { Pa[s] = a; Ph[s] = w; }
            else        { Pa[s] *= a; Ph[s] = fmaf(a, Ph[s], w); }
        }
    }

    // phase 2a: intra-wave inclusive scan (wave-synchronous, no barriers)
    #pragma unroll
    for (int off = 1; off <= 32; off <<= 1) {
        float qa[SS], qh[SS];
        #pragma unroll
        for (int s = 0; s < SS; ++s) {
            qa[s] = __shfl_up(Pa[s], off);
            qh[s] = __shfl_up(Ph[s], off);
        }
        if (lane >= off) {
            #pragma unroll
            for (int s = 0; s < SS; ++s) {
                Ph[s] = fmaf(Pa[s], qh[s], Ph[s]);
                Pa[s] *= qa[s];
            }
        }
    }
    // phase 2b: wave totals -> LDS, compose wave prefix in registers
    if (lane == 63) {
        #pragma unroll
        for (int s = 0; s < SS; ++s) { wta[wvi][s] = Pa[s]; wtb[wvi][s] = Ph[s]; }
    }
    __syncthreads();
    float Wb[SS];
    #pragma unroll
    for (int s = 0; s < SS; ++s) Wb[s] = 0.f;
    for (int w = 0; w < wvi; ++w) {
        #pragma unroll
        for (int s = 0; s < SS; ++s)
            Wb[s] = fmaf(wta[w][s], Wb[s], wtb[w][s]);
    }
    // full inclusive offset (h0 = 0): Fb = Pa*Wb + Ph
    float Fb[SS];
    #pragma unroll
    for (int s = 0; s < SS; ++s) Fb[s] = fmaf(Pa[s], Wb[s], Ph[s]);

    // exclusive prefix for this thread
    float h[SS];
    #pragma unroll
    for (int s = 0; s < SS; ++s) {
        float up = __shfl_up(Fb[s], 1);
        h[s] = (lane == 0) ? ((wvi == 0) ? 0.f : Wb[s]) : up;
    }

    // phase 3: recompute + emit
    float Dv = Dp[di];
    #pragma unroll
    for (int j = 0; j < 4; ++j) {
        float u = dtv[j] * xv[j];
        const float* bt = bc + (rb + j) * (2 * SS);
        float acc = 0.f;
        #pragma unroll
        for (int s = 0; s < SS; ++s) {
            float a = ex_f(dtv[j] * A[s]);
            h[s] = fmaf(a, h[s], u * bt[s]);
            acc = fmaf(h[s], bt[SS + s], acc);
        }
        float zv = bf2f(xz[(rb + j) * (2 * DII) + DII + di]);
        y[(rb + j) * DII + di] = (u16)f2bf(fmaf(Dv, xv[j], acc) * silu_f(zv));
    }
}

// ---------------------------------------------------------------- key-split flash attention: 512 thr, 2 wave-groups
__global__ __launch_bounds__(512) void fattn_k(
    const u16* __restrict__ qkv, const u16* __restrict__ vt,
    const float* __restrict__ ts, const int* __restrict__ mask,
    const float* __restrict__ decay, u16* __restrict__ out) {
    __shared__ __align__(16) char ksm[2][8192];
    __shared__ __align__(16) char vsm[2][8192];
    __shared__ __align__(16) char psm[16384];      // 8 waves x 2KB
    __shared__ float mrg[256][25];                  // group-1 partials
    __shared__ float tsk[2][64];
    __shared__ int   msk[2][64];

    int tid = threadIdx.x;
    int grp = tid >> 8;            // wave-group 0/1
    int lt  = tid & 255;
    int lane = tid & 63;
    int wvi = (tid >> 6) & 3;      // q-row block
    int qt = blockIdx.x & 15;
    int h  = (blockIdx.x >> 4) & 3;
    int b  = blockIdx.x >> 6;
    int q0 = qt * 64;
    int g = lane >> 4, c = lane & 15;

    bh8 qf[2];
    {
        const u16* qrow = qkv + ((size_t)(b * LL + q0 + wvi * 16 + c)) * (3 * DD) + h * DH;
        qf[0] = *(const bh8*)(qrow + g * 8);
        qf[1] = *(const bh8*)(qrow + 32 + g * 8);
    }
    float tq[4];
    #pragma unroll
    for (int j = 0; j < 4; ++j) tq[j] = ts[b * LL + q0 + wvi * 16 + g * 4 + j];
    float spd = sp_f(decay[h]);

    f32x4 o[4];
    #pragma unroll
    for (int n = 0; n < 4; ++n) o[n] = (f32x4){0.f, 0.f, 0.f, 0.f};
    float mrow[4] = {-INFINITY, -INFINITY, -INFINITY, -INFINITY};
    float drow[4] = {0.f, 0.f, 0.f, 0.f};

    char* pw = psm + (tid >> 6) * 2048;   // per physical wave

    int nt = (qt + 2) >> 1;
    for (int it = 0; it < nt; ++it) {
        int kt = it * 2 + grp;
        bool act = (kt <= qt);
        int k0 = kt * 64;
        __syncthreads();
        if (act) {
            int row = lt >> 2, qq = lt & 3;
            unsigned sw = (unsigned)((row & 7) << 4);
            unsigned base = (unsigned)(row * 128 + qq * 32);
            const u16* kr = qkv + ((size_t)(b * LL + k0 + row)) * (3 * DD) + DD + h * DH + qq * 16;
            *(bh8*)(ksm[grp] + (base ^ sw)) = *(const bh8*)(kr);
            *(bh8*)(ksm[grp] + ((base + 16) ^ sw)) = *(const bh8*)(kr + 8);
            const u16* vr = vt + ((((size_t)b * HH + h) * DH + row) << 10) + k0 + qq * 16;
            *(bh8*)(vsm[grp] + (base ^ sw)) = *(const bh8*)(vr);
            *(bh8*)(vsm[grp] + ((base + 16) ^ sw)) = *(const bh8*)(vr + 8);
            if (lt < 64) { tsk[grp][lt] = ts[b * LL + k0 + lt]; msk[grp][lt] = mask[b * LL + k0 + lt]; }
        }
        __syncthreads();
        if (!act) continue;

        f32x4 sf[4];
        #pragma unroll
        for (int n = 0; n < 4; ++n) sf[n] = (f32x4){0.f, 0.f, 0.f, 0.f};
        #pragma unroll
        for (int ks = 0; ks < 2; ++ks) {
            #pragma unroll
            for (int nf = 0; nf < 4; ++nf) {
                int rr = nf * 16 + c;
                bh8 kf = *(const bh8*)(ksm[grp] + (unsigned)((rr * 128 + ks * 64 + g * 16) ^ ((rr & 7) << 4)));
                sf[nf] = __builtin_amdgcn_mfma_f32_16x16x32_bf16(qf[ks], kf, sf[nf], 0, 0, 0);
            }
        }
        float mnew[4] = {mrow[0], mrow[1], mrow[2], mrow[3]};
        #pragma unroll
        for (int nf = 0; nf < 4; ++nf) {
            int kk = c + 16 * nf;
            float tk = tsk[grp][kk];
            bool md = (msk[grp][kk] == 0);
            #pragma unroll
            for (int j = 0; j < 4; ++j) {
                int qrow = q0 + wvi * 16 + g * 4 + j;
                float s = sf[nf][j] * 0.125f - spd * fabsf(tq[j] - tk) * (1.f / 24.f);
                bool dead = md || (k0 + kk > qrow);
                s = dead ? -INFINITY : s;
                sf[nf][j] = s;
                mnew[j] = fmaxf(mnew[j], s);
            }
        }
        #pragma unroll
        for (int off = 1; off <= 8; off <<= 1)
            #pragma unroll
            for (int j = 0; j < 4; ++j) mnew[j] = fmaxf(mnew[j], __shfl_xor(mnew[j], off));
        float scl[4], psum[4];
        #pragma unroll
        for (int j = 0; j < 4; ++j) {
            scl[j] = (mnew[j] == -INFINITY) ? 1.f : ex_f(mrow[j] - mnew[j]);
            psum[j] = 0.f;
            mrow[j] = mnew[j];
        }
        #pragma unroll
        for (int nf = 0; nf < 4; ++nf) {
            #pragma unroll
            for (int j = 0; j < 4; ++j) {
                float s = sf[nf][j];
                float p = (s == -INFINITY) ? 0.f : ex_f(s - mrow[j]);
                psum[j] += p;
                int row = g * 4 + j;
                *(short*)(pw + (unsigned)((row * 128 + (c + 16 * nf) * 2) ^ ((row & 7) << 4))) = f2bf(p);
            }
        }
        #pragma unroll
        for (int off = 1; off <= 8; off <<= 1)
            #pragma unroll
            for (int j = 0; j < 4; ++j) psum[j] += __shfl_xor(psum[j], off);
        #pragma unroll
        for (int j = 0; j < 4; ++j) drow[j] = drow[j] * scl[j] + psum[j];
        #pragma unroll
        for (int n = 0; n < 4; ++n)
            #pragma unroll
            for (int j = 0; j < 4; ++j) o[n][j] *= scl[j];
        #pragma unroll
        for (int ks = 0; ks < 2; ++ks) {
            bh8 pf = *(const bh8*)(pw + (unsigned)((c * 128 + ks * 64 + g * 16) ^ ((c & 7) << 4)));
            #pragma unroll
            for (int n = 0; n < 4; ++n) {
                int rr = n * 16 + c;
                bh8 vf = *(const bh8*)(vsm[grp] + (unsigned)((rr * 128 + ks * 64 + g * 16) ^ ((rr & 7) << 4)));
                o[n] = __builtin_amdgcn_mfma_f32_16x16x32_bf16(pf, vf, o[n], 0, 0, 0);
            }
        }
    }

    // merge group-1 partials into group-0, write out
    __syncthreads();
    if (grp == 1) {
        float* m_ = mrg[lt];
        #pragma unroll
        for (int j = 0; j < 4; ++j) { m_[j] = mrow[j]; m_[4 + j] = drow[j]; }
        #pragma unroll
        for (int n = 0; n < 4; ++n)
            #pragma unroll
            for (int j = 0; j < 4; ++j) m_[8 + n * 4 + j] = o[n][j];
    }
    __syncthreads();
    if (grp == 0) {
        float* m_ = mrg[lt];
        #pragma unroll
        for (int j = 0; j < 4; ++j) {
            float m1 = m_[j], d1 = m_[4 + j];
            float mm = fmaxf(mrow[j], m1);
            float s0 = (mrow[j] == -INFINITY) ? 0.f : ex_f(mrow[j] - mm);
            float s1 = (m1 == -INFINITY) ? 0.f : ex_f(m1 - mm);
            drow[j] = drow[j] * s0 + d1 * s1;
            #pragma unroll
            for (int n = 0; n < 4; ++n)
                o[n][j] = o[n][j] * s0 + m_[8 + n * 4 + j] * s1;
        }
        #pragma unroll
        for (int n = 0; n < 4; ++n) {
            #pragma unroll
            for (int j = 0; j < 4; ++j) {
                int qrow = q0 + wvi * 16 + g * 4 + j;
                out[((size_t)(b * LL + qrow)) * DD + h * DH + c + 16 * n] = (u16)f2bf(o[n][j] / drow[j]);
            }
        }
    }
}

// ---------------------------------------------------------------- readm / mort heads (bf16 xn)
__global__ __launch_bounds__(64) void heads_k(
    const u16* __restrict__ xn, const float* __restrict__ re_w, const float* __restrict__ re_b,
    const float* __restrict__ mo_w, const float* __restrict__ mo_b, float* __restrict__ out) {
    int lane = threadIdx.x;
    int b = blockIdx.x & 3;
    int which = blockIdx.x >> 2;
    const float* wv = which ? mo_w : re_w;
    const u16* row = xn + (size_t)b * LL * DD;
    float s = 0.f;
    #pragma unroll
    for (int d = 0; d < DD / 64; ++d) s = fmaf(bf2f(row[lane + d * 64]), wv[lane + d * 64], s);
    #pragma unroll
    for (int o = 32; o >= 1; o >>= 1) s += __shfl_xor(s, o);
    if (lane == 0) out[(size_t)VV * BL + which * 4 + b] = s + (which ? mo_b[0] : re_b[0]);
}

// ================================================================ host
extern "C" void kernel_launch(void* const* d_in, const int* in_sizes, int n_in,
                              void* d_out, int out_size, void* d_ws, size_t ws_size,
                              hipStream_t stream) {
    const int*   ids      = (const int*)  d_in[0];
    const int*   typ      = (const int*)  d_in[1];
    const float* ts       = (const float*)d_in[2];
    const int*   amask    = (const int*)  d_in[3];
    const float* tok_emb  = (const float*)d_in[4];
    const float* type_emb = (const float*)d_in[5];
    const float* te_freq  = (const float*)d_in[6];
    const float* te_phase = (const float*)d_in[7];
    const float* te_w     = (const float*)d_in[8];
    const float* te_b     = (const float*)d_in[9];
    const float* m_norm_g = (const float*)d_in[10];
    const float* m_norm_b = (const float*)d_in[11];
    const float* m_in_w   = (const float*)d_in[12];
    const float* m_conv_w = (const float*)d_in[13];
    const float* m_conv_b = (const float*)d_in[14];
    const float* m_xproj  = (const float*)d_in[15];
    const float* m_dt_w   = (const float*)d_in[16];
    const float* m_dt_b   = (const float*)d_in[17];
    const float* m_Alog   = (const float*)d_in[18];
    const float* m_D      = (const float*)d_in[19];
    const float* m_out_w  = (const float*)d_in[20];
    const float* a_norm_g = (const float*)d_in[21];
    const float* a_norm_b = (const float*)d_in[22];
    const float* a_qkv_w  = (const float*)d_in[23];
    const float* a_out_w  = (const float*)d_in[24];
    const float* a_decay  = (const float*)d_in[25];
    const float* a_ffg    = (const float*)d_in[26];
    const float* a_ffb    = (const float*)d_in[27];
    const float* a_ff1    = (const float*)d_in[28];
    const float* a_ff2    = (const float*)d_in[29];
    const float* f_g      = (const float*)d_in[30];
    const float* f_b      = (const float*)d_in[31];
    const float* lm_w     = (const float*)d_in[32];
    const float* re_w     = (const float*)d_in[33];
    const float* re_b     = (const float*)d_in[34];
    const float* mo_w     = (const float*)d_in[35];
    const float* mo_b     = (const float*)d_in[36];

    float* out = (float*)d_out;
    float* ws  = (float*)d_ws;

    // workspace layout (float offsets)
    float* x    = ws;                     // BL*D fp32
    u16*   xnb  = (u16*)(ws + 1048576);   // BL*D bf16
    u16*   t1   = (u16*)(ws + 1572864);   // BL*1024 bf16 xz/qkv
    u16*   b1   = (u16*)(ws + 3670016);   // BL*1024 bf16 multi (feat/xb/attnout/ffh)
    u16*   b2   = (u16*)(ws + 5767168);   // BL*512 bf16 y
    float* t3   = ws + 6815744;           // BL*512 fp32 dt
    float* t5   = ws + 8912896;           // BL*32 fp32 bc
    u16*   vtb  = (u16*)(ws + 9043968);   // V^T bf16 [b][h][dh][L] (1,048,576 u16)
    u16*   wbuf = (u16*)(ws + 9568256);   // non-lm weights bf16
    u16*   wlm  = (u16*)(ws + 12402688);  // lm_w bf16 (8,192,000 u16)

    const u16* w_te  = wbuf;
    const u16* w_qkv = wbuf + 65536;
    const u16* w_ao  = wbuf + 458752;
    const u16* w_ff1 = wbuf + 589824;
    const u16* w_ff2 = wbuf + 1114112;
    const u16* w_min = wbuf + 1638400;
    const u16* w_mo  = wbuf + 3211264;
    const u16* w_dtx = wbuf + 3997696;

    // 0. convert all weights (incl lm_w) to bf16
    cvtall_k<<<(WB_TOT + LM_TOT) / 1024, 256, 0, stream>>>(
        te_w, a_qkv_w, a_out_w, a_ff1, a_ff2, m_in_w, m_out_w, m_dt_w, m_xproj, lm_w, wbuf, wlm);
    // 1. time features -> b1 (bf16)
    feat_k<<<BL, 256, 0, stream>>>(ts, te_freq, te_phase, b1);
    // 2. x = feat @ te_w^T + te_b + tok_emb[ids] + type_emb[typ]
    bgemm32_k<4, true, false><<<dim3(4, BL / 32), 256, 0, stream>>>(
        b1, w_te, te_b, nullptr, x, BL, DD, DD, ids, typ, tok_emb, type_emb);

    int mi = 0, ai = 0;
    for (int i = 0; i < 8; ++i) {
        if ((i + 1) % 4 == 0) {
            // ------------- attention block ai
            lngemm_k<0, true, true><<<dim3(12, BL / 64), 256, 0, stream>>>(
                x, a_norm_g + ai * DD, a_norm_b + ai * DD,
                w_qkv + (size_t)ai * 196608, t1, vtb, BL, 3 * DD);
            fattn_k<<<BB * HH * (LL / 64), 512, 0, stream>>>(
                t1, vtb, ts, amask, a_decay + ai * HH, b1);
            bgemm32_k<0, false, true><<<dim3(4, BL / 32), 256, 0, stream>>>(
                b1, w_ao + (size_t)ai * 65536, nullptr, x, x, BL, DD, DD,
                nullptr, nullptr, nullptr, nullptr);
            lngemm_k<1, true, false><<<dim3(16, BL / 64), 256, 0, stream>>>(
                x, a_ffg + ai * DD, a_ffb + ai * DD,
                w_ff1 + (size_t)ai * 262144, b1, nullptr, BL, 4 * DD);
            bgemm32_k<0, false, true><<<dim3(4, BL / 32), 256, 0, stream>>>(
                b1, w_ff2 + (size_t)ai * 262144, nullptr, x, x, BL, DD, 4 * DD,
                nullptr, nullptr, nullptr, nullptr);
            ++ai;
        } else {
            // ------------- mamba block mi
            lngemm_k<0, true, false><<<dim3(16, BL / 64), 256, 0, stream>>>(
                x, m_norm_g + mi * DD, m_norm_b + mi * DD,
                w_min + (size_t)mi * 262144, t1, nullptr, BL, 2 * DII);
            conv_k<<<(BL * DII) / 256, 256, 0, stream>>>(
                t1, m_conv_w + (size_t)mi * DII * DCC, m_conv_b + mi * DII, b1);
            bgemm_k<3, true, false, false><<<dim3(9, BL / 64), 256, 0, stream>>>(
                b1, w_dtx + (size_t)mi * 278528, m_dt_b + mi * DII, nullptr, t3, t5, BL, 544, DII);
            scan_k<<<BB * DII, 256, 0, stream>>>(
                t3, b1, t5, t1, m_Alog + (size_t)mi * DII * SS, m_D + mi * DII, b2);
            bgemm32_k<0, false, true><<<dim3(4, BL / 32), 256, 0, stream>>>(
                b2, w_mo + (size_t)mi * 131072, nullptr, x, x, BL, DD, DII,
                nullptr, nullptr, nullptr, nullptr);
            ++mi;
        }
    }

    // final layernorm -> xnb (bf16, feeds lm GEMM + heads)
    ln_k<<<BL, 256, 0, stream>>>(x, f_g, f_b, xnb);
    // lm logits -> out[0 : BL*V]   (XCD-chunked MFMA)
    mgemmL_k<<<dim3(32, 256), 256, 0, stream>>>(xnb, wlm, out, BL, VV, DD);
    // readm / mort heads
    heads_k<<<8, 64, 0, stream>>>(xnb, re_w, re_b, mo_w, mo_b, out);
}

// Round 14
// 1166.942 us; speedup vs baseline: 1.0253x; 1.0253x over previous
//
#include <hip/hip_runtime.h>
#include <hip/hip_bf16.h>
#include <math.h>

// Problem constants
#define BB 4
#define LL 1024
#define BL (BB*LL)          // 4096 tokens
#define DD 256
#define VV 32000
#define HH 4
#define DH 64
#define SS 16
#define DCC 4
#define DII 512

typedef float f32x4 __attribute__((ext_vector_type(4)));
typedef short bh8  __attribute__((ext_vector_type(8)));   // 8 bf16 (bit pattern)
typedef unsigned short u16;

// native-rate transcendentals (v_exp_f32 / v_log_f32)
__device__ __forceinline__ float ex_f(float x) { return __expf(x); }
__device__ __forceinline__ float sp_f(float x) {        // softplus
    return fmaxf(x, 0.f) + __logf(1.f + __expf(-fabsf(x)));
}
__device__ __forceinline__ float silu_f(float x) {
    return x / (1.f + __expf(-x));
}
__device__ __forceinline__ short f2bf(float f) {
    __hip_bfloat16 h = __float2bfloat16(f);
    short s; __builtin_memcpy(&s, &h, 2); return s;
}
__device__ __forceinline__ float bf2f(u16 u) {
    unsigned v = ((unsigned)u) << 16;
    float f; __builtin_memcpy(&f, &v, 4); return f;
}

// ---------------------------------------------------------------- all weights fp32->bf16 (one pass, incl lm_w)
#define WB_TOT 5668864
#define LM_TOT 8192000
__global__ void cvtall_k(const float* __restrict__ te_w, const float* __restrict__ a_qkv,
                         const float* __restrict__ a_out, const float* __restrict__ a_ff1,
                         const float* __restrict__ a_ff2, const float* __restrict__ m_in,
                         const float* __restrict__ m_out, const float* __restrict__ m_dt,
                         const float* __restrict__ m_xp, const float* __restrict__ lm,
                         u16* __restrict__ dst, u16* __restrict__ dlm) {
    long i = ((long)blockIdx.x * 256 + threadIdx.x) * 4;
    const float* src; long off; u16* d; long doff;
    if (i >= WB_TOT) {
        long j = i - WB_TOT;
        if (j >= LM_TOT) return;
        src = lm; off = j; d = dlm; doff = j;
    } else {
        d = dst; doff = i;
        if      (i < 65536)   { src = te_w;  off = i; }
        else if (i < 458752)  { src = a_qkv; off = i - 65536; }
        else if (i < 589824)  { src = a_out; off = i - 458752; }
        else if (i < 1114112) { src = a_ff1; off = i - 589824; }
        else if (i < 1638400) { src = a_ff2; off = i - 1114112; }
        else if (i < 3211264) { src = m_in;  off = i - 1638400; }
        else if (i < 3997696) { src = m_out; off = i - 3211264; }
        else {
            long l = i - 3997696;
            int mi = (int)(l / 278528);
            long r = l - (long)mi * 278528;
            if (r < 262144) { src = m_dt + (long)mi * 262144; off = r; }
            else            { src = m_xp + (long)mi * 16384;  off = r - 262144; }
        }
    }
    float4 v = *(const float4*)(src + off);
    ushort4 u;
    u.x = (u16)f2bf(v.x); u.y = (u16)f2bf(v.y);
    u.z = (u16)f2bf(v.z); u.w = (u16)f2bf(v.w);
    *(ushort4*)(d + doff) = u;
}

// ---------------------------------------------------------------- time feat (bf16 out)
__global__ void feat_k(const float* __restrict__ ts, const float* __restrict__ freq,
                       const float* __restrict__ phase, u16* __restrict__ feat) {
    int row = blockIdx.x, t = threadIdx.x;
    float tv = ts[row];
    int d = t & 127;
    float f = sp_f(freq[d]);
    float arg = tv * f + phase[d];
    feat[(size_t)row * DD + t] = (u16)f2bf((t < 128) ? sinf(arg) : cosf(arg));
}

// ---------------------------------------------------------------- layernorm (final only, bf16 out)
__global__ void ln_k(const float* __restrict__ x, const float* __restrict__ g,
                     const float* __restrict__ bbias, u16* __restrict__ out) {
    __shared__ float red[8];
    int row = blockIdx.x, t = threadIdx.x;
    float v = x[(size_t)row * DD + t];
    float s = v;
    #pragma unroll
    for (int o = 32; o >= 1; o >>= 1) s += __shfl_xor(s, o);
    if ((t & 63) == 0) red[t >> 6] = s;
    __syncthreads();
    float mean = (red[0] + red[1] + red[2] + red[3]) * (1.f / 256.f);
    float d = v - mean;
    float s2 = d * d;
    #pragma unroll
    for (int o = 32; o >= 1; o >>= 1) s2 += __shfl_xor(s2, o);
    if ((t & 63) == 0) red[4 + (t >> 6)] = s2;
    __syncthreads();
    float var = (red[4] + red[5] + red[6] + red[7]) * (1.f / 256.f);
    out[(size_t)row * DD + t] = (u16)f2bf(d * rsqrtf(var + 1e-5f) * g[t] + bbias[t]);
}

// ---------------------------------------------------------------- LN-fused 64x64-tile MFMA GEMM (K=256 fixed)
template <int ACT, bool BOUT, bool VT>
__global__ __launch_bounds__(256) void lngemm_k(
    const float* __restrict__ X, const float* __restrict__ g, const float* __restrict__ bb,
    const u16* __restrict__ W, void* __restrict__ outv, u16* __restrict__ vt,
    int M, int N) {
    __shared__ __align__(16) char Abf[32768];   // 64 rows x 256 bf16, swizzled
    __shared__ __align__(16) char Ws[8192];     // 64 rows x 64 bf16 per k-step
    __shared__ float gs[256], bs[256];
    int tid = threadIdx.x;
    int bm = blockIdx.y * 64, bn = blockIdx.x * 64;
    gs[tid] = g[tid]; bs[tid] = bb[tid];

    int row = tid >> 2, part = tid & 3;
    const float* xr = X + (size_t)(bm + row) * 256 + part * 64;
    float4 vv[16];
    float s = 0.f, sq = 0.f;
    #pragma unroll
    for (int i = 0; i < 16; ++i) {
        vv[i] = *(const float4*)(xr + i * 4);
        s  += vv[i].x + vv[i].y + vv[i].z + vv[i].w;
        sq += vv[i].x * vv[i].x + vv[i].y * vv[i].y + vv[i].z * vv[i].z + vv[i].w * vv[i].w;
    }
    s += __shfl_xor(s, 1);  s += __shfl_xor(s, 2);
    sq += __shfl_xor(sq, 1); sq += __shfl_xor(sq, 2);
    float mean = s * (1.f / 256.f);
    float rstd = rsqrtf(sq * (1.f / 256.f) - mean * mean + 1e-5f);
    __syncthreads();   // gs/bs visible
    #pragma unroll
    for (int i8 = 0; i8 < 8; ++i8) {
        bh8 p;
        #pragma unroll
        for (int j = 0; j < 8; ++j) {
            int e = i8 * 8 + j;
            float v = (j & 3) == 0 ? vv[e >> 2].x : (j & 3) == 1 ? vv[e >> 2].y
                    : (j & 3) == 2 ? vv[e >> 2].z : vv[e >> 2].w;
            int c = part * 64 + e;
            p[j] = f2bf((v - mean) * rstd * gs[c] + bs[c]);
        }
        *(bh8*)(Abf + (unsigned)((row * 512 + part * 128 + i8 * 16) ^ ((row & 7) << 4))) = p;
    }
    __syncthreads();

    int lane = tid & 63, wv = tid >> 6;
    int wm = wv >> 1, wn = wv & 1;
    int ro = lane & 15, kg = lane >> 4;
    f32x4 acc[2][2];
    #pragma unroll
    for (int i = 0; i < 2; ++i)
        #pragma unroll
        for (int j = 0; j < 2; ++j) acc[i][j] = (f32x4){0.f, 0.f, 0.f, 0.f};

    const u16* gw = W + (size_t)(bn + row) * 256 + part * 16;
    bool wvalid = (bn + row) < N;
    unsigned swb = (unsigned)(row * 128 + part * 32);
    unsigned sx  = (unsigned)((row & 7) << 4);
    for (int kk = 0; kk < 256; kk += 64) {
        if (kk) __syncthreads();
        bh8 w0 = {}, w1 = {};
        if (wvalid) { w0 = *(const bh8*)(gw + kk); w1 = *(const bh8*)(gw + kk + 8); }
        *(bh8*)(Ws + (swb ^ sx)) = w0;
        *(bh8*)(Ws + ((swb + 16) ^ sx)) = w1;
        __syncthreads();
        #pragma unroll
        for (int ks = 0; ks < 2; ++ks) {
            bh8 af[2], bf_[2];
            #pragma unroll
            for (int m = 0; m < 2; ++m) {
                int r = wm * 32 + m * 16 + ro;
                af[m] = *(const bh8*)(Abf + (unsigned)((r * 512 + kk * 2 + ks * 64 + kg * 16) ^ ((r & 7) << 4)));
            }
            #pragma unroll
            for (int n = 0; n < 2; ++n) {
                int r = wn * 32 + n * 16 + ro;
                bf_[n] = *(const bh8*)(Ws + (unsigned)((r * 128 + ks * 64 + kg * 16) ^ ((r & 7) << 4)));
            }
            #pragma unroll
            for (int m = 0; m < 2; ++m)
                #pragma unroll
                for (int n = 0; n < 2; ++n)
                    acc[m][n] = __builtin_amdgcn_mfma_f32_16x16x32_bf16(af[m], bf_[n], acc[m][n], 0, 0, 0);
        }
    }

    float* outf = (float*)outv;
    u16*   outb = (u16*)outv;
    int cr = (lane >> 4) * 4, cc = lane & 15;
    #pragma unroll
    for (int mf = 0; mf < 2; ++mf) {
        #pragma unroll
        for (int nf = 0; nf < 2; ++nf) {
            int n = bn + wn * 32 + nf * 16 + cc;
            if (n >= N) continue;
            int mbase = bm + wm * 32 + mf * 16 + cr;
            f32x4 a = acc[mf][nf];
            #pragma unroll
            for (int r = 0; r < 4; ++r) {
                float v = a[r];
                if (ACT == 1) v = silu_f(v);
                if (BOUT) outb[(size_t)(mbase + r) * N + n] = (u16)f2bf(v);
                else      outf[(size_t)(mbase + r) * N + n] = v;
            }
            if (VT && n >= 512) {
                int hh = (n - 512) >> 6, dd = (n - 512) & 63;
                int b_ = mbase >> 10, l = mbase & 1023;
                ushort4 uv;
                uv.x = (u16)f2bf(acc[mf][nf][0]); uv.y = (u16)f2bf(acc[mf][nf][1]);
                uv.z = (u16)f2bf(acc[mf][nf][2]); uv.w = (u16)f2bf(acc[mf][nf][3]);
                *(ushort4*)(vt + ((((size_t)b_ * HH + hh) * DH + dd) << 10) + l) = uv;
            }
        }
    }
}

// ---------------------------------------------------------------- 64x64-tile MFMA GEMM (dtx)
// ACT 3: dtx (n<512: softplus+bias -> outf; else raw -> out2)
template <int ACT, bool HASB, bool HASR, bool BOUT>
__global__ __launch_bounds__(256) void bgemm_k(
    const u16* __restrict__ A, const u16* __restrict__ W,
    const float* __restrict__ bias, const float* __restrict__ res,
    void* __restrict__ outv, float* __restrict__ out2, int M, int N, int K) {
    __shared__ __align__(16) char lds[16384];
    char* As = lds;
    char* Ws = lds + 8192;
    int tid = threadIdx.x;
    int bm = blockIdx.y * 64, bn = blockIdx.x * 64;
    int row = tid >> 2, q = tid & 3;
    int lane = tid & 63, wv = tid >> 6;
    int wm = wv >> 1, wn = wv & 1;
    int ro = lane & 15, kg = lane >> 4;

    f32x4 acc[2][2];
    #pragma unroll
    for (int i = 0; i < 2; ++i)
        #pragma unroll
        for (int j = 0; j < 2; ++j) acc[i][j] = (f32x4){0.f, 0.f, 0.f, 0.f};

    const u16* ga = A + (size_t)(bm + row) * K + q * 16;
    const u16* gw = W + (size_t)(bn + row) * K + q * 16;
    bool wvalid = (bn + row) < N;
    unsigned swb = (unsigned)(row * 128 + q * 32);
    unsigned sx  = (unsigned)((row & 7) << 4);

    for (int kk = 0; kk < K; kk += 64) {
        if (kk) __syncthreads();
        {
            *(bh8*)(As + (swb ^ sx)) = *(const bh8*)(ga);
            *(bh8*)(As + ((swb + 16) ^ sx)) = *(const bh8*)(ga + 8);
            bh8 w0 = {}, w1 = {};
            if (wvalid) { w0 = *(const bh8*)(gw); w1 = *(const bh8*)(gw + 8); }
            *(bh8*)(Ws + (swb ^ sx)) = w0;
            *(bh8*)(Ws + ((swb + 16) ^ sx)) = w1;
        }
        ga += 64; gw += 64;
        __syncthreads();
        #pragma unroll
        for (int ks = 0; ks < 2; ++ks) {
            bh8 af[2], bf_[2];
            #pragma unroll
            for (int m = 0; m < 2; ++m) {
                int r = wm * 32 + m * 16 + ro;
                af[m] = *(const bh8*)(As + (unsigned)((r * 128 + ks * 64 + kg * 16) ^ ((r & 7) << 4)));
            }
            #pragma unroll
            for (int n = 0; n < 2; ++n) {
                int r = wn * 32 + n * 16 + ro;
                bf_[n] = *(const bh8*)(Ws + (unsigned)((r * 128 + ks * 64 + kg * 16) ^ ((r & 7) << 4)));
            }
            #pragma unroll
            for (int m = 0; m < 2; ++m)
                #pragma unroll
                for (int n = 0; n < 2; ++n)
                    acc[m][n] = __builtin_amdgcn_mfma_f32_16x16x32_bf16(af[m], bf_[n], acc[m][n], 0, 0, 0);
        }
    }

    float* outf = (float*)outv;
    u16*   outb = (u16*)outv;
    int cr = (lane >> 4) * 4, cc = lane & 15;
    #pragma unroll
    for (int mf = 0; mf < 2; ++mf) {
        #pragma unroll
        for (int nf = 0; nf < 2; ++nf) {
            int n = bn + wn * 32 + nf * 16 + cc;
            if (n >= N) continue;
            int mbase = bm + wm * 32 + mf * 16 + cr;
            f32x4 a = acc[mf][nf];
            #pragma unroll
            for (int r = 0; r < 4; ++r) {
                float v = a[r];
                int m = mbase + r;
                if (ACT == 3) {
                    if (n < 512) outf[(size_t)m * 512 + n] = sp_f(v + bias[n]);
                    else         out2[(size_t)m * 32 + (n - 512)] = v;
                } else {
                    if (HASB) v += bias[n];
                    if (ACT == 1) v = silu_f(v);
                    if (HASR) v += res[(size_t)m * N + n];
                    if (BOUT) outb[(size_t)m * N + n] = (u16)f2bf(v);
                    else      outf[(size_t)m * N + n] = v;
                }
            }
        }
    }
}

// ---------------------------------------------------------------- 32x64-tile GEMM, 2 blocks/CU for N=256 sites
template <int ACT, bool HASB, bool HASR>
__global__ __launch_bounds__(256) void bgemm32_k(
    const u16* __restrict__ A, const u16* __restrict__ W,
    const float* __restrict__ bias, const float* __restrict__ res,
    float* __restrict__ out, int M, int N, int K,
    const int* __restrict__ ids, const int* __restrict__ typ,
    const float* __restrict__ tok, const float* __restrict__ tpe) {
    __shared__ __align__(16) char As[4096];     // 32 rows x 64 bf16
    __shared__ __align__(16) char Ws[8192];     // 64 rows x 64 bf16
    int tid = threadIdx.x;
    int bm = blockIdx.y * 32, bn = blockIdx.x * 64;
    int lane = tid & 63, wv = tid >> 6;
    int wm = wv >> 1, wn = wv & 1;              // wave: 16 rows x 32 cols
    int ro = lane & 15, kg = lane >> 4;

    f32x4 acc[2];
    acc[0] = (f32x4){0.f, 0.f, 0.f, 0.f};
    acc[1] = (f32x4){0.f, 0.f, 0.f, 0.f};

    int arow = tid >> 3, aq = tid & 7;
    const u16* ga = A + (size_t)(bm + arow) * K + aq * 8;
    unsigned aswb = (unsigned)(arow * 128 + aq * 16);
    unsigned asx  = (unsigned)((arow & 7) << 4);
    int wrow = tid >> 2, wq = tid & 3;
    const u16* gw = W + (size_t)(bn + wrow) * K + wq * 16;
    unsigned wswb = (unsigned)(wrow * 128 + wq * 32);
    unsigned wsx  = (unsigned)((wrow & 7) << 4);

    for (int kk = 0; kk < K; kk += 64) {
        if (kk) __syncthreads();
        *(bh8*)(As + (aswb ^ asx)) = *(const bh8*)(ga);
        *(bh8*)(Ws + (wswb ^ wsx)) = *(const bh8*)(gw);
        *(bh8*)(Ws + ((wswb + 16) ^ wsx)) = *(const bh8*)(gw + 8);
        ga += 64; gw += 64;
        __syncthreads();
        #pragma unroll
        for (int ks = 0; ks < 2; ++ks) {
            int r = wm * 16 + ro;
            bh8 af = *(const bh8*)(As + (unsigned)((r * 128 + ks * 64 + kg * 16) ^ ((r & 7) << 4)));
            #pragma unroll
            for (int n = 0; n < 2; ++n) {
                int rr = wn * 32 + n * 16 + ro;
                bh8 bf_ = *(const bh8*)(Ws + (unsigned)((rr * 128 + ks * 64 + kg * 16) ^ ((rr & 7) << 4)));
                acc[n] = __builtin_amdgcn_mfma_f32_16x16x32_bf16(af, bf_, acc[n], 0, 0, 0);
            }
        }
    }

    int cr = (lane >> 4) * 4, cc = lane & 15;
    #pragma unroll
    for (int nf = 0; nf < 2; ++nf) {
        int n = bn + wn * 32 + nf * 16 + cc;
        int mbase = bm + wm * 16 + cr;
        #pragma unroll
        for (int r = 0; r < 4; ++r) {
            float v = acc[nf][r];
            int m = mbase + r;
            if (ACT == 4) {
                v += bias[n] + tok[(size_t)ids[m] * DD + n] + tpe[(size_t)typ[m] * DD + n];
            } else {
                if (HASB) v += bias[n];
                if (HASR) v += res[(size_t)m * N + n];
            }
            out[(size_t)m * N + n] = v;
        }
    }
}

// ---------------------------------------------------------------- lm-head GEMM: bf16 A and W, XCD-chunked
__global__ __launch_bounds__(256) void mgemmL_k(
    const u16* __restrict__ A, const u16* __restrict__ W,
    float* __restrict__ out, int M, int N, int K) {
    __shared__ __align__(16) char lds[32768];
    char* As = lds;
    char* Ws = lds + 16384;
    int lid = blockIdx.y * 32 + blockIdx.x;
    int xcd = lid & 7, wk = lid >> 3;
    int nt = xcd * 32 + (wk >> 5);
    int mt = wk & 31;
    if (nt * 128 >= N) return;
    int bm = mt * 128, bn = nt * 128;

    int tid = threadIdx.x;
    int row = tid >> 1, half = tid & 1;
    int lane = tid & 63, wv = tid >> 6;
    int wm = wv >> 1, wn = wv & 1;
    int ro = lane & 15, kg = lane >> 4;

    f32x4 acc[4][4];
    #pragma unroll
    for (int i = 0; i < 4; ++i)
        #pragma unroll
        for (int j = 0; j < 4; ++j) acc[i][j] = (f32x4){0.f, 0.f, 0.f, 0.f};

    const u16* ga = A + (size_t)(bm + row) * K + half * 32;
    const u16* gw = W + (size_t)(bn + row) * K + half * 32;
    unsigned swb = (unsigned)(row * 128 + half * 64);
    unsigned sx  = (unsigned)((row & 7) << 4);

    for (int kk = 0; kk < K; kk += 64) {
        if (kk) __syncthreads();
        #pragma unroll
        for (int j = 0; j < 4; ++j) {
            *(bh8*)(As + ((swb + j * 16) ^ sx)) = *(const bh8*)(ga + j * 8);
            *(bh8*)(Ws + ((swb + j * 16) ^ sx)) = *(const bh8*)(gw + j * 8);
        }
        ga += 64; gw += 64;
        __syncthreads();
        #pragma unroll
        for (int ks = 0; ks < 2; ++ks) {
            bh8 af[4], bf_[4];
            #pragma unroll
            for (int m = 0; m < 4; ++m) {
                int r = wm * 64 + m * 16 + ro;
                af[m] = *(const bh8*)(As + (unsigned)((r * 128 + ks * 64 + kg * 16) ^ ((r & 7) << 4)));
            }
            #pragma unroll
            for (int n = 0; n < 4; ++n) {
                int r = wn * 64 + n * 16 + ro;
                bf_[n] = *(const bh8*)(Ws + (unsigned)((r * 128 + ks * 64 + kg * 16) ^ ((r & 7) << 4)));
            }
            #pragma unroll
            for (int m = 0; m < 4; ++m)
                #pragma unroll
                for (int n = 0; n < 4; ++n)
                    acc[m][n] = __builtin_amdgcn_mfma_f32_16x16x32_bf16(af[m], bf_[n], acc[m][n], 0, 0, 0);
        }
    }

    int cr = (lane >> 4) * 4, cc = lane & 15;
    #pragma unroll
    for (int mf = 0; mf < 4; ++mf) {
        #pragma unroll
        for (int nf = 0; nf < 4; ++nf) {
            int n = bn + wn * 64 + nf * 16 + cc;
            int mbase = bm + wm * 64 + mf * 16 + cr;
            f32x4 a = acc[mf][nf];
            #pragma unroll
            for (int r = 0; r < 4; ++r)
                out[(size_t)(mbase + r) * N + n] = a[r];
        }
    }
}

// ---------------------------------------------------------------- depthwise causal conv + silu (vectorized, 8 ch/thread)
__global__ void conv_k(const u16* __restrict__ xz, const float* __restrict__ w,
                       const float* __restrict__ cb, u16* __restrict__ xbb) {
    int idx = blockIdx.x * 256 + threadIdx.x;   // BL * (DII/8) threads
    int c8 = idx & 63;
    int m  = idx >> 6;
    int l  = m & (LL - 1);
    int c0 = c8 * 8;

    float s[8];
    #pragma unroll
    for (int e = 0; e < 8; ++e) s[e] = cb[c0 + e];
    float4 cw4[8];
    #pragma unroll
    for (int e = 0; e < 8; ++e) cw4[e] = *(const float4*)(w + (size_t)(c0 + e) * DCC);

    #pragma unroll
    for (int j = 0; j < DCC; ++j) {
        int ll = l - (DCC - 1) + j;
        if (ll >= 0) {
            bh8 v = *(const bh8*)(xz + (size_t)(m - (DCC - 1) + j) * (2 * DII) + c0);
            #pragma unroll
            for (int e = 0; e < 8; ++e) {
                float wj = (j == 0) ? cw4[e].x : (j == 1) ? cw4[e].y : (j == 2) ? cw4[e].z : cw4[e].w;
                s[e] = fmaf(wj, bf2f((u16)v[e]), s[e]);
            }
        }
    }
    bh8 o;
    #pragma unroll
    for (int e = 0; e < 8; ++e) o[e] = f2bf(silu_f(s[e]));
    *(bh8*)(xbb + (size_t)m * DII + c0) = o;
}

// ---------------------------------------------------------------- fused selective scan: one block per (b,di)
// LDS Hillis-Steele (r12 proven form)
__global__ __launch_bounds__(256) void scan_k(
    const float* __restrict__ dt, const u16* __restrict__ xb,
    const float* __restrict__ bc, const u16* __restrict__ xz,
    const float* __restrict__ Alog, const float* __restrict__ Dp,
    u16* __restrict__ y) {
    __shared__ float pa[SS][257];
    __shared__ float ph[SS][257];
    int di = blockIdx.x & (DII - 1);
    int b  = blockIdx.x >> 9;
    int t  = threadIdx.x;
    int l0 = t * 4;
    size_t rb = (size_t)(b * LL + l0);

    float A[SS];
    #pragma unroll
    for (int s = 0; s < SS; ++s) A[s] = -ex_f(Alog[di * SS + s]);

    float dtv[4], xv[4];
    #pragma unroll
    for (int j = 0; j < 4; ++j) {
        dtv[j] = dt[(rb + j) * DII + di];
        xv[j]  = bf2f(xb[(rb + j) * DII + di]);
    }

    float Pa[SS], Ph[SS];
    #pragma unroll
    for (int j = 0; j < 4; ++j) {
        float u = dtv[j] * xv[j];
        const float* bt = bc + (rb + j) * (2 * SS);
        #pragma unroll
        for (int s = 0; s < SS; ++s) {
            float a = ex_f(dtv[j] * A[s]);
            float w = u * bt[s];
            if (j == 0) { Pa[s] = a; Ph[s] = w; }
            else        { Pa[s] *= a; Ph[s] = fmaf(a, Ph[s], w); }
        }
    }
    #pragma unroll
    for (int s = 0; s < SS; ++s) { pa[s][t] = Pa[s]; ph[s][t] = Ph[s]; }
    __syncthreads();

    #pragma unroll
    for (int off = 1; off < 256; off <<= 1) {
        float qa[SS], qh[SS];
        bool has = (t >= off);
        if (has) {
            #pragma unroll
            for (int s = 0; s < SS; ++s) { qa[s] = pa[s][t - off]; qh[s] = ph[s][t - off]; }
        }
        __syncthreads();
        if (has) {
            #pragma unroll
            for (int s = 0; s < SS; ++s) {
                ph[s][t] = fmaf(pa[s][t], qh[s], ph[s][t]);
                pa[s][t] *= qa[s];
            }
        }
        __syncthreads();
    }

    float h[SS];
    if (t == 0) {
        #pragma unroll
        for (int s = 0; s < SS; ++s) h[s] = 0.f;
    } else {
        #pragma unroll
        for (int s = 0; s < SS; ++s) h[s] = ph[s][t - 1];
    }
    float Dv = Dp[di];
    #pragma unroll
    for (int j = 0; j < 4; ++j) {
        float u = dtv[j] * xv[j];
        const float* bt = bc + (rb + j) * (2 * SS);
        float acc = 0.f;
        #pragma unroll
        for (int s = 0; s < SS; ++s) {
            float a = ex_f(dtv[j] * A[s]);
            h[s] = fmaf(a, h[s], u * bt[s]);
            acc = fmaf(h[s], bt[SS + s], acc);
        }
        float zv = bf2f(xz[(rb + j) * (2 * DII) + DII + di]);
        y[(rb + j) * DII + di] = (u16)f2bf(fmaf(Dv, xv[j], acc) * silu_f(zv));
    }
}

// ---------------------------------------------------------------- key-split flash attention: 512 thr, 2 wave-groups
__global__ __launch_bounds__(512) void fattn_k(
    const u16* __restrict__ qkv, const u16* __restrict__ vt,
    const float* __restrict__ ts, const int* __restrict__ mask,
    const float* __restrict__ decay, u16* __restrict__ out) {
    __shared__ __align__(16) char ksm[2][8192];
    __shared__ __align__(16) char vsm[2][8192];
    __shared__ __align__(16) char psm[16384];      // 8 waves x 2KB
    __shared__ float mrg[256][25];                  // group-1 partials
    __shared__ float tsk[2][64];
    __shared__ int   msk[2][64];

    int tid = threadIdx.x;
    int grp = tid >> 8;            // wave-group 0/1
    int lt  = tid & 255;
    int lane = tid & 63;
    int wvi = (tid >> 6) & 3;      // q-row block
    int qt = blockIdx.x & 15;
    int h  = (blockIdx.x >> 4) & 3;
    int b  = blockIdx.x >> 6;
    int q0 = qt * 64;
    int g = lane >> 4, c = lane & 15;

    bh8 qf[2];
    {
        const u16* qrow = qkv + ((size_t)(b * LL + q0 + wvi * 16 + c)) * (3 * DD) + h * DH;
        qf[0] = *(const bh8*)(qrow + g * 8);
        qf[1] = *(const bh8*)(qrow + 32 + g * 8);
    }
    float tq[4];
    #pragma unroll
    for (int j = 0; j < 4; ++j) tq[j] = ts[b * LL + q0 + wvi * 16 + g * 4 + j];
    float spd = sp_f(decay[h]);

    f32x4 o[4];
    #pragma unroll
    for (int n = 0; n < 4; ++n) o[n] = (f32x4){0.f, 0.f, 0.f, 0.f};
    float mrow[4] = {-INFINITY, -INFINITY, -INFINITY, -INFINITY};
    float drow[4] = {0.f, 0.f, 0.f, 0.f};

    char* pw = psm + (tid >> 6) * 2048;   // per physical wave

    int nt = (qt + 2) >> 1;
    for (int it = 0; it < nt; ++it) {
        int kt = it * 2 + grp;
        bool act = (kt <= qt);
        int k0 = kt * 64;
        __syncthreads();
        if (act) {
            int row = lt >> 2, qq = lt & 3;
            unsigned sw = (unsigned)((row & 7) << 4);
            unsigned base = (unsigned)(row * 128 + qq * 32);
            const u16* kr = qkv + ((size_t)(b * LL + k0 + row)) * (3 * DD) + DD + h * DH + qq * 16;
            *(bh8*)(ksm[grp] + (base ^ sw)) = *(const bh8*)(kr);
            *(bh8*)(ksm[grp] + ((base + 16) ^ sw)) = *(const bh8*)(kr + 8);
            const u16* vr = vt + ((((size_t)b * HH + h) * DH + row) << 10) + k0 + qq * 16;
            *(bh8*)(vsm[grp] + (base ^ sw)) = *(const bh8*)(vr);
            *(bh8*)(vsm[grp] + ((base + 16) ^ sw)) = *(const bh8*)(vr + 8);
            if (lt < 64) { tsk[grp][lt] = ts[b * LL + k0 + lt]; msk[grp][lt] = mask[b * LL + k0 + lt]; }
        }
        __syncthreads();
        if (!act) continue;

        f32x4 sf[4];
        #pragma unroll
        for (int n = 0; n < 4; ++n) sf[n] = (f32x4){0.f, 0.f, 0.f, 0.f};
        #pragma unroll
        for (int ks = 0; ks < 2; ++ks) {
            #pragma unroll
            for (int nf = 0; nf < 4; ++nf) {
                int rr = nf * 16 + c;
                bh8 kf = *(const bh8*)(ksm[grp] + (unsigned)((rr * 128 + ks * 64 + g * 16) ^ ((rr & 7) << 4)));
                sf[nf] = __builtin_amdgcn_mfma_f32_16x16x32_bf16(qf[ks], kf, sf[nf], 0, 0, 0);
            }
        }
        float mnew[4] = {mrow[0], mrow[1], mrow[2], mrow[3]};
        #pragma unroll
        for (int nf = 0; nf < 4; ++nf) {
            int kk = c + 16 * nf;
            float tk = tsk[grp][kk];
            bool md = (msk[grp][kk] == 0);
            #pragma unroll
            for (int j = 0; j < 4; ++j) {
                int qrow = q0 + wvi * 16 + g * 4 + j;
                float s = sf[nf][j] * 0.125f - spd * fabsf(tq[j] - tk) * (1.f / 24.f);
                bool dead = md || (k0 + kk > qrow);
                s = dead ? -INFINITY : s;
                sf[nf][j] = s;
                mnew[j] = fmaxf(mnew[j], s);
            }
        }
        #pragma unroll
        for (int off = 1; off <= 8; off <<= 1)
            #pragma unroll
            for (int j = 0; j < 4; ++j) mnew[j] = fmaxf(mnew[j], __shfl_xor(mnew[j], off));
        float scl[4], psum[4];
        #pragma unroll
        for (int j = 0; j < 4; ++j) {
            scl[j] = (mnew[j] == -INFINITY) ? 1.f : ex_f(mrow[j] - mnew[j]);
            psum[j] = 0.f;
            mrow[j] = mnew[j];
        }
        #pragma unroll
        for (int nf = 0; nf < 4; ++nf) {
            #pragma unroll
            for (int j = 0; j < 4; ++j) {
                float s = sf[nf][j];
                float p = (s == -INFINITY) ? 0.f : ex_f(s - mrow[j]);
                psum[j] += p;
                int row = g * 4 + j;
                *(short*)(pw + (unsigned)((row * 128 + (c + 16 * nf) * 2) ^ ((row & 7) << 4))) = f2bf(p);
            }
        }
        #pragma unroll
        for (int off = 1; off <= 8; off <<= 1)
            #pragma unroll
            for (int j = 0; j < 4; ++j) psum[j] += __shfl_xor(psum[j], off);
        #pragma unroll
        for (int j = 0; j < 4; ++j) drow[j] = drow[j] * scl[j] + psum[j];
        #pragma unroll
        for (int n = 0; n < 4; ++n)
            #pragma unroll
            for (int j = 0; j < 4; ++j) o[n][j] *= scl[j];
        #pragma unroll
        for (int ks = 0; ks < 2; ++ks) {
            bh8 pf = *(const bh8*)(pw + (unsigned)((c * 128 + ks * 64 + g * 16) ^ ((c & 7) << 4)));
            #pragma unroll
            for (int n = 0; n < 4; ++n) {
                int rr = n * 16 + c;
                bh8 vf = *(const bh8*)(vsm[grp] + (unsigned)((rr * 128 + ks * 64 + g * 16) ^ ((rr & 7) << 4)));
                o[n] = __builtin_amdgcn_mfma_f32_16x16x32_bf16(pf, vf, o[n], 0, 0, 0);
            }
        }
    }

    // merge group-1 partials into group-0, write out
    __syncthreads();
    if (grp == 1) {
        float* m_ = mrg[lt];
        #pragma unroll
        for (int j = 0; j < 4; ++j) { m_[j] = mrow[j]; m_[4 + j] = drow[j]; }
        #pragma unroll
        for (int n = 0; n < 4; ++n)
            #pragma unroll
            for (int j = 0; j < 4; ++j) m_[8 + n * 4 + j] = o[n][j];
    }
    __syncthreads();
    if (grp == 0) {
        float* m_ = mrg[lt];
        #pragma unroll
        for (int j = 0; j < 4; ++j) {
            float m1 = m_[j], d1 = m_[4 + j];
            float mm = fmaxf(mrow[j], m1);
            float s0 = (mrow[j] == -INFINITY) ? 0.f : ex_f(mrow[j] - mm);
            float s1 = (m1 == -INFINITY) ? 0.f : ex_f(m1 - mm);
            drow[j] = drow[j] * s0 + d1 * s1;
            #pragma unroll
            for (int n = 0; n < 4; ++n)
                o[n][j] = o[n][j] * s0 + m_[8 + n * 4 + j] * s1;
        }
        #pragma unroll
        for (int n = 0; n < 4; ++n) {
            #pragma unroll
            for (int j = 0; j < 4; ++j) {
                int qrow = q0 + wvi * 16 + g * 4 + j;
                out[((size_t)(b * LL + qrow)) * DD + h * DH + c + 16 * n] = (u16)f2bf(o[n][j] / drow[j]);
            }
        }
    }
}

// ---------------------------------------------------------------- readm / mort heads (bf16 xn)
__global__ __launch_bounds__(64) void heads_k(
    const u16* __restrict__ xn, const float* __restrict__ re_w, const float* __restrict__ re_b,
    const float* __restrict__ mo_w, const float* __restrict__ mo_b, float* __restrict__ out) {
    int lane = threadIdx.x;
    int b = blockIdx.x & 3;
    int which = blockIdx.x >> 2;
    const float* wv = which ? mo_w : re_w;
    const u16* row = xn + (size_t)b * LL * DD;
    float s = 0.f;
    #pragma unroll
    for (int d = 0; d < DD / 64; ++d) s = fmaf(bf2f(row[lane + d * 64]), wv[lane + d * 64], s);
    #pragma unroll
    for (int o = 32; o >= 1; o >>= 1) s += __shfl_xor(s, o);
    if (lane == 0) out[(size_t)VV * BL + which * 4 + b] = s + (which ? mo_b[0] : re_b[0]);
}

// ================================================================ host
extern "C" void kernel_launch(void* const* d_in, const int* in_sizes, int n_in,
                              void* d_out, int out_size, void* d_ws, size_t ws_size,
                              hipStream_t stream) {
    const int*   ids      = (const int*)  d_in[0];
    const int*   typ      = (const int*)  d_in[1];
    const float* ts       = (const float*)d_in[2];
    const int*   amask    = (const int*)  d_in[3];
    const float* tok_emb  = (const float*)d_in[4];
    const float* type_emb = (const float*)d_in[5];
    const float* te_freq  = (const float*)d_in[6];
    const float* te_phase = (const float*)d_in[7];
    const float* te_w     = (const float*)d_in[8];
    const float* te_b     = (const float*)d_in[9];
    const float* m_norm_g = (const float*)d_in[10];
    const float* m_norm_b = (const float*)d_in[11];
    const float* m_in_w   = (const float*)d_in[12];
    const float* m_conv_w = (const float*)d_in[13];
    const float* m_conv_b = (const float*)d_in[14];
    const float* m_xproj  = (const float*)d_in[15];
    const float* m_dt_w   = (const float*)d_in[16];
    const float* m_dt_b   = (const float*)d_in[17];
    const float* m_Alog   = (const float*)d_in[18];
    const float* m_D      = (const float*)d_in[19];
    const float* m_out_w  = (const float*)d_in[20];
    const float* a_norm_g = (const float*)d_in[21];
    const float* a_norm_b = (const float*)d_in[22];
    const float* a_qkv_w  = (const float*)d_in[23];
    const float* a_out_w  = (const float*)d_in[24];
    const float* a_decay  = (const float*)d_in[25];
    const float* a_ffg    = (const float*)d_in[26];
    const float* a_ffb    = (const float*)d_in[27];
    const float* a_ff1    = (const float*)d_in[28];
    const float* a_ff2    = (const float*)d_in[29];
    const float* f_g      = (const float*)d_in[30];
    const float* f_b      = (const float*)d_in[31];
    const float* lm_w     = (const float*)d_in[32];
    const float* re_w     = (const float*)d_in[33];
    const float* re_b     = (const float*)d_in[34];
    const float* mo_w     = (const float*)d_in[35];
    const float* mo_b     = (const float*)d_in[36];

    float* out = (float*)d_out;
    float* ws  = (float*)d_ws;

    // workspace layout (float offsets)
    float* x    = ws;                     // BL*D fp32
    u16*   xnb  = (u16*)(ws + 1048576);   // BL*D bf16
    u16*   t1   = (u16*)(ws + 1572864);   // BL*1024 bf16 xz/qkv
    u16*   b1   = (u16*)(ws + 3670016);   // BL*1024 bf16 multi (feat/xb/attnout/ffh)
    u16*   b2   = (u16*)(ws + 5767168);   // BL*512 bf16 y
    float* t3   = ws + 6815744;           // BL*512 fp32 dt
    float* t5   = ws + 8912896;           // BL*32 fp32 bc
    u16*   vtb  = (u16*)(ws + 9043968);   // V^T bf16 [b][h][dh][L] (1,048,576 u16)
    u16*   wbuf = (u16*)(ws + 9568256);   // non-lm weights bf16
    u16*   wlm  = (u16*)(ws + 12402688);  // lm_w bf16 (8,192,000 u16)

    const u16* w_te  = wbuf;
    const u16* w_qkv = wbuf + 65536;
    const u16* w_ao  = wbuf + 458752;
    const u16* w_ff1 = wbuf + 589824;
    const u16* w_ff2 = wbuf + 1114112;
    const u16* w_min = wbuf + 1638400;
    const u16* w_mo  = wbuf + 3211264;
    const u16* w_dtx = wbuf + 3997696;

    // 0. convert all weights (incl lm_w) to bf16
    cvtall_k<<<(WB_TOT + LM_TOT) / 1024, 256, 0, stream>>>(
        te_w, a_qkv_w, a_out_w, a_ff1, a_ff2, m_in_w, m_out_w, m_dt_w, m_xproj, lm_w, wbuf, wlm);
    // 1. time features -> b1 (bf16)
    feat_k<<<BL, 256, 0, stream>>>(ts, te_freq, te_phase, b1);
    // 2. x = feat @ te_w^T + te_b + tok_emb[ids] + type_emb[typ]
    bgemm32_k<4, true, false><<<dim3(4, BL / 32), 256, 0, stream>>>(
        b1, w_te, te_b, nullptr, x, BL, DD, DD, ids, typ, tok_emb, type_emb);

    int mi = 0, ai = 0;
    for (int i = 0; i < 8; ++i) {
        if ((i + 1) % 4 == 0) {
            // ------------- attention block ai
            lngemm_k<0, true, true><<<dim3(12, BL / 64), 256, 0, stream>>>(
                x, a_norm_g + ai * DD, a_norm_b + ai * DD,
                w_qkv + (size_t)ai * 196608, t1, vtb, BL, 3 * DD);
            fattn_k<<<BB * HH * (LL / 64), 512, 0, stream>>>(
                t1, vtb, ts, amask, a_decay + ai * HH, b1);
            bgemm32_k<0, false, true><<<dim3(4, BL / 32), 256, 0, stream>>>(
                b1, w_ao + (size_t)ai * 65536, nullptr, x, x, BL, DD, DD,
                nullptr, nullptr, nullptr, nullptr);
            lngemm_k<1, true, false><<<dim3(16, BL / 64), 256, 0, stream>>>(
                x, a_ffg + ai * DD, a_ffb + ai * DD,
                w_ff1 + (size_t)ai * 262144, b1, nullptr, BL, 4 * DD);
            bgemm32_k<0, false, true><<<dim3(4, BL / 32), 256, 0, stream>>>(
                b1, w_ff2 + (size_t)ai * 262144, nullptr, x, x, BL, DD, 4 * DD,
                nullptr, nullptr, nullptr, nullptr);
            ++ai;
        } else {
            // ------------- mamba block mi
            lngemm_k<0, true, false><<<dim3(16, BL / 64), 256, 0, stream>>>(
                x, m_norm_g + mi * DD, m_norm_b + mi * DD,
                w_min + (size_t)mi * 262144, t1, nullptr, BL, 2 * DII);
            conv_k<<<(BL * (DII / 8)) / 256, 256, 0, stream>>>(
                t1, m_conv_w + (size_t)mi * DII * DCC, m_conv_b + mi * DII, b1);
            bgemm_k<3, true, false, false><<<dim3(9, BL / 64), 256, 0, stream>>>(
                b1, w_dtx + (size_t)mi * 278528, m_dt_b + mi * DII, nullptr, t3, t5, BL, 544, DII);
            scan_k<<<BB * DII, 256, 0, stream>>>(
                t3, b1, t5, t1, m_Alog + (size_t)mi * DII * SS, m_D + mi * DII, b2);
            bgemm32_k<0, false, true><<<dim3(4, BL / 32), 256, 0, stream>>>(
                b2, w_mo + (size_t)mi * 131072, nullptr, x, x, BL, DD, DII,
                nullptr, nullptr, nullptr, nullptr);
            ++mi;
        }
    }

    // final layernorm -> xnb (bf16, feeds lm GEMM + heads)
    ln_k<<<BL, 256, 0, stream>>>(x, f_g, f_b, xnb);
    // lm logits -> out[0 : BL*V]   (XCD-chunked MFMA)
    mgemmL_k<<<dim3(32, 256), 256, 0, stream>>>(xnb, wlm, out, BL, VV, DD);
    // readm / mort heads
    heads_k<<<8, 64, 0, stream>>>(xnb, re_w, re_b, mo_w, mo_b, out);
}